// Round 11
// baseline (253.589 us; speedup 1.0000x reference)
//
#include <hip/hip_runtime.h>

#define H 32
#define SEQ 512
#define BM 16          // batch rows per block (= MFMA N)
#define NTHREADS 512   // 8 waves: wv0-3 = L1 (units 8w..8w+7), wv4-7 = L2 (lag-2)
#define HSTRIDE 40     // halves per h-row: 80B rows, 16B-aligned b128 frags

typedef _Float16 half8 __attribute__((ext_vector_type(8)));
typedef _Float16 f16x2 __attribute__((ext_vector_type(2)));
typedef __attribute__((ext_vector_type(4))) float f32x4;
typedef __attribute__((ext_vector_type(2))) float f32x2;

#define L2E 1.44269504088896340736f

__device__ __forceinline__ float rcp_(float x)  { return __builtin_amdgcn_rcpf(x); }
__device__ __forceinline__ float exp2_(float x) { return __builtin_amdgcn_exp2f(x); }  // raw v_exp_f32
#define MFMA16(A, B, C) __builtin_amdgcn_mfma_f32_16x16x32_f16((A), (B), (C), 0, 0, 0)

// Two LSTM cells evaluated as a packed pair (v_pk_* f32): element 0 = cell a,
// element 1 = cell b. Per-element ops/order identical to the verified scalar cell
// (5 v_exp + 2 v_rcp each). This is the exact-LSTM trans minimum.
__device__ __forceinline__ f32x2 cell2(const f32x4& ga, const f32x4& gb, f32x2& cst) {
    f32x2 ei = {exp2_(ga[0]), exp2_(gb[0])};
    f32x2 ef = {exp2_(ga[1]), exp2_(gb[1])};
    f32x2 eg = {exp2_(ga[2]), exp2_(gb[2])};
    f32x2 eo = {exp2_(ga[3]), exp2_(gb[3])};
    f32x2 A  = 1.f + ei, F = 1.f + ef;
    f32x2 Gp = eg + 1.f, Gm = eg - 1.f;
    f32x2 t1 = A * Gp;
    f32x2 num = __builtin_elementwise_fma(cst, t1, Gm * F);
    f32x2 den = F * t1;
    f32x2 r1 = {rcp_(den.x), rcp_(den.y)};
    f32x2 cn = num * r1;
    cst = cn;
    f32x2 arg = __builtin_elementwise_min(cn * (2.f * L2E), (f32x2)80.f);
    f32x2 ec = {exp2_(arg.x), exp2_(arg.y)};
    f32x2 dh = (1.f + eo) * (ec + 1.f);
    f32x2 r2 = {rcp_(dh.x), rcp_(dh.y)};
    return (ec - 1.f) * r2;
}

__global__ __launch_bounds__(NTHREADS, 2) void lstm_kernel(
    const float* __restrict__ x,      // [4096,512]
    const float* __restrict__ w_ih0,  // [128,1]
    const float* __restrict__ w_hh0,  // [128,32]
    const float* __restrict__ b_ih0, const float* __restrict__ b_hh0,
    const float* __restrict__ w_ih1,  // [128,32]
    const float* __restrict__ w_hh1,  // [128,32]
    const float* __restrict__ b_ih1, const float* __restrict__ b_hh1,
    const float* __restrict__ fc1_w,  // [16,32]
    const float* __restrict__ fc1_b,  // [16]
    const float* __restrict__ fc2_w,  // [1,16]
    const float* __restrict__ fc2_b,  // [1]
    float* __restrict__ out)          // [4096]
{
    __shared__ __align__(16) float    xbufT[(SEQ + 1) * BM];      // +1 step pad: clampless prefetch
    __shared__ __align__(16) _Float16 h1s[4][BM * HSTRIDE];       // 4-deep h1 ring (fp16)
    __shared__ __align__(16) _Float16 h2s[2][BM * HSTRIDE];       // ping-pong h2 (fp16)
    __shared__ __align__(16) float    h2f[BM * 33];
    __shared__ __align__(16) float    yb[BM * 17];

    const int tid  = threadIdx.x;
    const int lane = tid & 63;
    const int wv   = tid >> 6;          // wave id 0..7 (wave i -> SIMD i%4)
    const int role = wv >> 2;           // 0 = layer-1 wave, 1 = layer-2 wave
    const int w    = wv & 3;            // role-local wave id 0..3: owns units 8w..8w+7
    const int c    = lane & 15;         // frag free-index / batch col
    const int q    = lane >> 4;         // k-quad / D row-group
    const int r0   = blockIdx.x * BM;

    // ---- stage x transposed: xbufT[s][row] ----
    {
        const int row = tid >> 5;           // 0..15
        const int s0  = (tid & 31) * 16;    // 16 steps per thread
        const float* xr = x + (size_t)(r0 + row) * SEQ + s0;
        #pragma unroll
        for (int i = 0; i < 16; i += 4) {
            float4 v = *(const float4*)&xr[i];
            xbufT[(s0 + i + 0) * BM + row] = v.x;
            xbufT[(s0 + i + 1) * BM + row] = v.y;
            xbufT[(s0 + i + 2) * BM + row] = v.z;
            xbufT[(s0 + i + 3) * BM + row] = v.w;
        }
    }
    for (int i = tid; i < 4 * BM * HSTRIDE; i += NTHREADS) ((_Float16*)h1s)[i] = (_Float16)0.f;
    for (int i = tid; i < 2 * BM * HSTRIDE; i += NTHREADS) ((_Float16*)h2s)[i] = (_Float16)0.f;

    // ---- W fragments (A-operand). Tile k of wave w: rows permuted
    // r -> (gate r&3, unit 8w + 2*(r>>2) + k), so lane (c,q) owns the ADJACENT
    // units 8w+2q (k=0) and 8w+2q+1 (k=1) -> single half2 h-write per step.
    // Gate scales folded (i,f,o: -L2E ; g: +2L2E) so cells use raw v_exp_f32.
    const float gsc[4] = { -L2E, -L2E, 2.f * L2E, -L2E };
    const float wsc = gsc[c & 3];
    const int kb = 8 * q;
    const int m = c;                    // batch row owned by this lane

    half8 wA[2], wB[2];                 // role 0: wA=w_hh0 ; role 1: wA=w_ih1, wB=w_hh1
    f32x4 biasv[2], wxv[2];
    #pragma unroll
    for (int k = 0; k < 2; ++k) {
        const int u     = 8 * w + 2 * q + k;            // unit of cell k for this lane
        const int worig = (c & 3) * H + 8 * w + 2 * (c >> 2) + k;
        if (role == 0) {
            const float* p = &w_hh0[worig * H + kb];
            #pragma unroll
            for (int j = 0; j < 8; ++j) wA[k][j] = (_Float16)(p[j] * wsc);
            #pragma unroll
            for (int g = 0; g < 4; ++g) {
                biasv[k][g] = (b_ih0[g * H + u] + b_hh0[g * H + u]) * gsc[g];
                wxv[k][g]   = w_ih0[g * H + u] * gsc[g];
            }
        } else {
            const float* p = &w_ih1[worig * H + kb];
            #pragma unroll
            for (int j = 0; j < 8; ++j) wA[k][j] = (_Float16)(p[j] * wsc);
            p = &w_hh1[worig * H + kb];
            #pragma unroll
            for (int j = 0; j < 8; ++j) wB[k][j] = (_Float16)(p[j] * wsc);
            #pragma unroll
            for (int g = 0; g < 4; ++g)
                biasv[k][g] = (b_ih1[g * H + u] + b_hh1[g * H + u]) * gsc[g];
        }
    }

    f32x2 cst = {0.f, 0.f};   // c-states of this lane's 2 cells
    f32x2 hl  = {0.f, 0.f};   // role 1: h2(511) per cell

    const int fofs  = c * HSTRIDE + kb;            // b128 frag read offset (halves)
    const int whofs = m * HSTRIDE + 8 * w + 2 * q; // half2 h write offset (halves, even)

    // L2 P-pipeline: P[tau&1] = W_ih1 @ h1(tau) + bias, produced at iteration
    // tau+1, consumed at iteration tau+2 (off the serial h2 chain).
    f32x4 P[2][2] = {};

    __syncthreads();

    // L1 waves carry the sequential critical chain: prefer them on the CU scheduler.
    if (role == 0) __builtin_amdgcn_s_setprio(1);

    float xv = xbufT[m];                   // prefetched x(t=0) (role-0 only uses it)

    // Iteration t: L1 computes step t (t<512); L2 finishes tau=t-2 and
    // precomputes P(t-1). h1 ring depth 4: write slot t&3=p, L1 reads (p+3)&3,
    // L2 reads (p+3)&3 (= h1(t-1)). h2 ping-pong: write (t-2)&1=p&1, read (p+1)&1.
    // P: consume [p&1], produce [(p+1)&1]. tb multiple of 4 -> all compile-time.
    for (int tb = 0; tb < 516; tb += 4) {
        #pragma unroll
        for (int p = 0; p < 4; ++p) {
            const int t = tb + p;
            if (role == 0) {
                if (t < 512) {
                    // x-term + bias pre-folded into accumulator (xv prefetched last iter)
                    f32x4 pre[2];
                    #pragma unroll
                    for (int k = 0; k < 2; ++k) {
                        #pragma unroll
                        for (int j = 0; j < 4; ++j) pre[k][j] = fmaf(xv, wxv[k][j], biasv[k][j]);
                    }
                    half8 a1 = *(const half8*)(&h1s[(p + 3) & 3][0] + fofs);   // h1(t-1)
                    f32x4 g0 = MFMA16(wA[0], a1, pre[0]);
                    f32x4 g1 = MFMA16(wA[1], a1, pre[1]);
                    f32x2 hv = cell2(g0, g1, cst);
                    f16x2 hp; hp[0] = (_Float16)hv.x; hp[1] = (_Float16)hv.y;
                    *(f16x2*)(&h1s[p][0] + whofs) = hp;                        // h1(t)
                    xv = xbufT[(t + 1) * BM + m];                              // prefetch x(t+1)
                }
            } else {
                if (t >= 2 && t < 514) {
                    // finish tau = t-2: only the h2-recurrence MFMA is on the chain
                    half8 a2 = *(const half8*)(&h2s[(p + 1) & 1][0] + fofs);   // h2(t-3)
                    f32x4 g0 = MFMA16(wB[0], a2, P[p & 1][0]);
                    f32x4 g1 = MFMA16(wB[1], a2, P[p & 1][1]);
                    f32x2 hv = cell2(g0, g1, cst);
                    hl = hv;
                    f16x2 hp; hp[0] = (_Float16)hv.x; hp[1] = (_Float16)hv.y;
                    *(f16x2*)(&h2s[p & 1][0] + whofs) = hp;                    // h2(t-2)
                }
                if (t >= 1 && t < 513) {
                    // precompute P(t-1) = W_ih1 @ h1(t-1) + bias (slack work)
                    half8 a1n = *(const half8*)(&h1s[(p + 3) & 3][0] + fofs);  // h1(t-1)
                    P[(p + 1) & 1][0] = MFMA16(wA[0], a1n, biasv[0]);
                    P[(p + 1) & 1][1] = MFMA16(wA[1], a1n, biasv[1]);
                }
            }
            __syncthreads();
        }
    }

    if (role == 0) __builtin_amdgcn_s_setprio(0);

    // ---- FC head ----
    if (role == 1) {
        h2f[m * 33 + (8 * w + 2 * q + 0)] = hl.x;
        h2f[m * 33 + (8 * w + 2 * q + 1)] = hl.y;
    }
    __syncthreads();
    if (tid < BM * 16) {
        int rr = tid >> 4, j = tid & 15;
        float acc = fc1_b[j];
        #pragma unroll
        for (int k = 0; k < H; ++k) acc += fc1_w[j * H + k] * h2f[rr * 33 + k];
        acc = acc >= 0.f ? acc : 0.2f * acc;
        yb[rr * 17 + j] = acc * fc2_w[j];
    }
    __syncthreads();
    if (tid < BM) {
        float acc = fc2_b[0];
        #pragma unroll
        for (int j = 0; j < 16; ++j) acc += yb[tid * 17 + j];
        out[r0 + tid] = acc;
    }
}

extern "C" void kernel_launch(void* const* d_in, const int* in_sizes, int n_in,
                              void* d_out, int out_size, void* d_ws, size_t ws_size,
                              hipStream_t stream) {
    const float* x     = (const float*)d_in[0];
    const float* w_ih0 = (const float*)d_in[1];
    const float* w_hh0 = (const float*)d_in[2];
    const float* b_ih0 = (const float*)d_in[3];
    const float* b_hh0 = (const float*)d_in[4];
    const float* w_ih1 = (const float*)d_in[5];
    const float* w_hh1 = (const float*)d_in[6];
    const float* b_ih1 = (const float*)d_in[7];
    const float* b_hh1 = (const float*)d_in[8];
    const float* fc1_w = (const float*)d_in[9];
    const float* fc1_b = (const float*)d_in[10];
    const float* fc2_w = (const float*)d_in[11];
    const float* fc2_b = (const float*)d_in[12];
    float* out = (float*)d_out;

    const int B = in_sizes[0] / SEQ;   // 4096
    hipLaunchKernelGGL(lstm_kernel, dim3(B / BM), dim3(NTHREADS), 0, stream,
                       x, w_ih0, w_hh0, b_ih0, b_hh0, w_ih1, w_hh1, b_ih1, b_hh1,
                       fc1_w, fc1_b, fc2_w, fc2_b, out);
}